// Round 1
// baseline (292.664 us; speedup 1.0000x reference)
//
#include <hip/hip_runtime.h>
#include <stdint.h>

#define INP 128
#define OUTD 128
#define WT_STRIDE 136   // k-stride (elements) for W' layout: +8 pad keeps ds_read_b128 16B-aligned, bank profile == contiguous
#define THREEFRY_PARTITIONABLE 1  // JAX >=0.5 default; flip to 0 if absmax ~1.5-3 (noise-scheme mismatch signature)

typedef __bf16 bf16x8 __attribute__((ext_vector_type(8)));
typedef float  floatx4 __attribute__((ext_vector_type(4)));

// ---------------- threefry2x32 (bit-exact vs jax._src.prng) ----------------
__device__ __forceinline__ uint32_t rotl32(uint32_t v, uint32_t n) {
  return (v << n) | (v >> (32u - n));
}
__device__ __forceinline__ void tf_round(uint32_t& x0, uint32_t& x1, uint32_t r) {
  x0 += x1; x1 = rotl32(x1, r); x1 ^= x0;
}
__device__ void threefry2x32(uint32_t k0, uint32_t k1, uint32_t c0, uint32_t c1,
                             uint32_t& o0, uint32_t& o1) {
  uint32_t k2 = k0 ^ k1 ^ 0x1BD11BDAu;
  uint32_t x0 = c0 + k0, x1 = c1 + k1;
  tf_round(x0,x1,13); tf_round(x0,x1,15); tf_round(x0,x1,26); tf_round(x0,x1,6);
  x0 += k1; x1 += k2 + 1u;
  tf_round(x0,x1,17); tf_round(x0,x1,29); tf_round(x0,x1,16); tf_round(x0,x1,24);
  x0 += k2; x1 += k0 + 2u;
  tf_round(x0,x1,13); tf_round(x0,x1,15); tf_round(x0,x1,26); tf_round(x0,x1,6);
  x0 += k0; x1 += k1 + 3u;
  tf_round(x0,x1,17); tf_round(x0,x1,29); tf_round(x0,x1,16); tf_round(x0,x1,24);
  x0 += k1; x1 += k2 + 4u;
  tf_round(x0,x1,13); tf_round(x0,x1,15); tf_round(x0,x1,26); tf_round(x0,x1,6);
  x0 += k2; x1 += k0 + 5u;
  o0 = x0; o1 = x1;
}

// Giles single-precision erfinv (same family as XLA's ErfInv32). Accuracy
// ~1e-6 abs; noise sensitivity of h is ~1e2 * eps -> utterly below budget.
__device__ float erfinv_giles(float x) {
  float w = -logf((1.0f - x) * (1.0f + x));
  float p;
  if (w < 5.0f) {
    w = w - 2.5f;
    p = 2.81022636e-08f;
    p = fmaf(p, w, 3.43273939e-07f);
    p = fmaf(p, w, -3.5233877e-06f);
    p = fmaf(p, w, -4.39150654e-06f);
    p = fmaf(p, w, 0.00021858087f);
    p = fmaf(p, w, -0.00125372503f);
    p = fmaf(p, w, -0.00417768164f);
    p = fmaf(p, w, 0.246640727f);
    p = fmaf(p, w, 1.50140941f);
  } else {
    w = sqrtf(w) - 3.0f;
    p = -0.000200214257f;
    p = fmaf(p, w, 0.000100950558f);
    p = fmaf(p, w, 0.00134934322f);
    p = fmaf(p, w, -0.00367342844f);
    p = fmaf(p, w, 0.00573950773f);
    p = fmaf(p, w, -0.0076224613f);
    p = fmaf(p, w, 0.00943887047f);
    p = fmaf(p, w, 1.00167406f);
    p = fmaf(p, w, 2.83297682f);
  }
  return p * x;
}

// jax.random.normal: u = uniform(lo=nextafter(-1,0), hi=1) from top-23 bits;
// note (hi-lo) rounds to exactly 2.0f in fp32, and f*2 is exact -> deterministic.
__device__ float normal_from_bits(uint32_t bits) {
  const float lo = -0.999999940395355224609375f;
  uint32_t fb = (bits >> 9) | 0x3F800000u;
  float f = __uint_as_float(fb) - 1.0f;
  float u = fmaxf(lo, f * 2.0f + lo);
  return 1.41421356237309515f * erfinv_giles(u);
}

__device__ __forceinline__ uint32_t rand_bits(uint32_t ka, uint32_t kb, int i, int half) {
#if THREEFRY_PARTITIONABLE
  (void)half;
  uint32_t o0, o1;
  threefry2x32(ka, kb, 0u, (uint32_t)i, o0, o1);
  return o0 ^ o1;
#else
  uint32_t c0 = (i < half) ? (uint32_t)i : (uint32_t)(i - half);
  uint32_t o0, o1;
  threefry2x32(ka, kb, c0, c0 + (uint32_t)half, o0, o1);
  return (i < half) ? o0 : o1;
#endif
}

// ---------------- setup: W' = quant(w) + noise  (bf16, transposed+padded) ----------------
__global__ __launch_bounds__(256) void setup_kernel(
    const float* __restrict__ w, const float* __restrict__ bias,
    __bf16* __restrict__ wt, float* __restrict__ biasEff) {
  __shared__ float red[8];
  const int tid = threadIdx.x;

  // w.max() over 16384 elements (exact, deterministic)
  float m = -3.4e38f;
  for (int i = tid; i < INP * OUTD; i += 256) m = fmaxf(m, w[i]);
  #pragma unroll
  for (int off = 1; off < 64; off <<= 1) m = fmaxf(m, __shfl_xor(m, off));
  // b.max() over 128 (bias is zeros in this problem, kept for generality)
  float bm = (tid < OUTD) ? bias[tid] : -3.4e38f;
  #pragma unroll
  for (int off = 1; off < 64; off <<= 1) bm = fmaxf(bm, __shfl_xor(bm, off));
  if ((tid & 63) == 0) { red[tid >> 6] = m; red[4 + (tid >> 6)] = bm; }
  __syncthreads();
  const float wmax = fmaxf(fmaxf(red[0], red[1]), fmaxf(red[2], red[3]));
  const float bmax = fmaxf(fmaxf(red[4], red[5]), fmaxf(red[6], red[7]));

  // k1, k2 = jax.random.split(jax.random.key(1234)); key data = (0, 1234)
  uint32_t k1a, k1b, k2a, k2b;
#if THREEFRY_PARTITIONABLE
  threefry2x32(0u, 1234u, 0u, 0u, k1a, k1b);
  threefry2x32(0u, 1234u, 0u, 1u, k2a, k2b);
#else
  { uint32_t a0, b0, a1, b1;
    threefry2x32(0u, 1234u, 0u, 2u, a0, b0);
    threefry2x32(0u, 1234u, 1u, 3u, a1, b1);
    k1a = a0; k1b = a1; k2a = b0; k2b = b1; }
#endif

  // W'[n][k] = quant_ste(w,1,8) + normal*wmax*0.1, stored bf16, k-contiguous
  for (int i = tid; i < INP * OUTD; i += 256) {
    float nrm = normal_from_bits(rand_bits(k1a, k1b, i, (INP * OUTD) / 2));
    int r = i >> 7, c = i & 127;       // w[r][c]: r = input dim (k), c = output (n)
    float wv = w[i];
    float wq = rintf(fminf(fmaxf(wv * 128.f, -127.f), 127.f)) * 0.0078125f;
    wt[c * WT_STRIDE + r] = (__bf16)(wq + (nrm * wmax) * 0.1f);
  }
  if (tid < OUTD) {
    float nrm = normal_from_bits(rand_bits(k2a, k2b, tid, OUTD / 2));
    float bv = bias[tid];
    float bq = rintf(fminf(fmaxf(bv * 128.f, -127.f), 127.f)) * 0.0078125f;
    biasEff[tid] = bq + (nrm * bmax) * 0.1f;
  }
}

// ---------------- main: quant(x) -> MFMA -> quant(out), 128x128 tile/block ----------------
__device__ __forceinline__ bf16x8 quant_a(const float* p, float s1, float r1) {
  floatx4 v0 = *(const floatx4*)p;
  floatx4 v1 = *(const floatx4*)(p + 4);
  bf16x8 a;
  #pragma unroll
  for (int i = 0; i < 4; ++i) {
    // xq = rint(clip(x*32, +/-127)) / 32 : exactly representable in bf16
    a[i]     = (__bf16)(rintf(fminf(fmaxf(v0[i] * s1, -127.f), 127.f)) * r1);
    a[i + 4] = (__bf16)(rintf(fminf(fmaxf(v1[i] * s1, -127.f), 127.f)) * r1);
  }
  return a;
}

__global__ __launch_bounds__(256) void linlayer_main(
    const float* __restrict__ x, const __bf16* __restrict__ wt,
    const float* __restrict__ biasEff, const float* __restrict__ a1p,
    const float* __restrict__ a2p, float* __restrict__ out) {
  __shared__ __attribute__((aligned(16))) __bf16 sW[OUTD * WT_STRIDE];
  __shared__ float sBias[OUTD];

  const int tid = threadIdx.x;

  // stage W' (34816 B) into LDS as uint4
  {
    const uint4* src = (const uint4*)wt;
    uint4* dst = (uint4*)sW;
    for (int i = tid; i < (OUTD * WT_STRIDE * 2) / 16; i += 256) dst[i] = src[i];
  }
  if (tid < OUTD) sBias[tid] = biasEff[tid];

  const float a1 = a1p[0], a2 = a2p[0];
  const float s1 = 128.0f / a1, r1 = a1 * 0.0078125f;  // 32, 1/32 (exact pow2)
  const float s2 = 128.0f / a2, r2 = a2 * 0.0078125f;  // 8, 0.125

  __syncthreads();

  const int wave = tid >> 6;
  const int lane = tid & 63;
  const int n16  = lane & 15;
  const int quad = lane >> 4;

  const long rowBase = (long)blockIdx.x * 128 + wave * 32;

  floatx4 acc[2][8];
  #pragma unroll
  for (int rt = 0; rt < 2; ++rt)
    #pragma unroll
    for (int ct = 0; ct < 8; ++ct) acc[rt][ct] = (floatx4)0.0f;

  const float* xp0 = x + (size_t)(rowBase + n16) * INP + quad * 8;
  const float* xp1 = xp0 + (size_t)16 * INP;

  #pragma unroll
  for (int kc = 0; kc < 4; ++kc) {
    bf16x8 afrag0 = quant_a(xp0 + kc * 32, s1, r1);
    bf16x8 afrag1 = quant_a(xp1 + kc * 32, s1, r1);
    const int kOff = kc * 32 + quad * 8;
    #pragma unroll
    for (int ct = 0; ct < 8; ++ct) {
      bf16x8 b = *(const bf16x8*)&sW[(ct * 16 + n16) * WT_STRIDE + kOff];
      acc[0][ct] = __builtin_amdgcn_mfma_f32_16x16x32_bf16(afrag0, b, acc[0][ct], 0, 0, 0);
      acc[1][ct] = __builtin_amdgcn_mfma_f32_16x16x32_bf16(afrag1, b, acc[1][ct], 0, 0, 0);
    }
  }

  // epilogue: out = rint(clip(h*8, +/-127)) * 0.125 ; C/D layout col=lane&15, row=quad*4+reg
  #pragma unroll
  for (int rt = 0; rt < 2; ++rt) {
    #pragma unroll
    for (int ct = 0; ct < 8; ++ct) {
      const int col = ct * 16 + n16;
      const float bsum = sBias[col];
      #pragma unroll
      for (int r = 0; r < 4; ++r) {
        const long row = rowBase + rt * 16 + quad * 4 + r;
        float h = acc[rt][ct][r] + bsum;
        float t = fminf(fmaxf(h * s2, -127.0f), 127.0f);
        out[(size_t)row * OUTD + col] = rintf(t) * r2;
      }
    }
  }
}

extern "C" void kernel_launch(void* const* d_in, const int* in_sizes, int n_in,
                              void* d_out, int out_size, void* d_ws, size_t ws_size,
                              hipStream_t stream) {
  const float* x    = (const float*)d_in[0];
  const float* w    = (const float*)d_in[1];
  const float* bias = (const float*)d_in[2];
  const float* a1   = (const float*)d_in[3];
  const float* a2   = (const float*)d_in[4];
  float* out = (float*)d_out;

  __bf16* wt      = (__bf16*)d_ws;                                     // 34816 B
  float* biasEff  = (float*)((char*)d_ws + OUTD * WT_STRIDE * 2);      // +512 B

  const int rows = in_sizes[0] / INP;     // 262144
  const int grid = rows / 128;            // 2048 blocks, one 128x128 tile each

  setup_kernel<<<1, 256, 0, stream>>>(w, bias, wt, biasEff);
  linlayer_main<<<grid, 256, 0, stream>>>(x, wt, biasEff, a1, a2, out);
}